// Round 1
// baseline (125.817 us; speedup 1.0000x reference)
//
#include <hip/hip_runtime.h>

// WaveKANLinear: out[n,o] = sum_d mexhat((ln(x)[n,d]-t[o,d])/s[o,d]) * ww[o,d]
//                           + silu(sum_d x[n,d]*bw[o,d])
// N=8192, D=128, O=128, float32.
// R6: ELIMINATE the workspace + prep kernel. Theory: the 2x 256MB
//     fillBufferAligned dispatches (40.8us each, 82% HBM) in the profile are
//     the harness poisoning d_ws inside the timed path -- 84% of dur_us.
//     Weight transform (softplus -> {t*is2, is2, ww*WWK, bw}) is now folded
//     into the per-chunk LDS staging: each weight transformed ONCE per block
//     (8.4M transforms device-wide ~1us), raw [O][D] arrays read coalesced
//     along d (same 128MB L2 volume as the old packed-ws reads). Register
//     prefetch+transform of chunk c+1 overlaps chunk c's compute.

#define D_DIM 128
#define O_DIM 128
#define ROWS  16     // rows per block
#define BLOCK 1024   // 16 waves: o = tid&127, pair g = tid>>7 (2 rows each)
#define CHUNK 16     // d-rows staged per LDS chunk
#define NCHUNK (D_DIM / CHUNK)
#define XSTRIDE 9    // float4 stride for s_x rows (pad: phase-1 write conflicts)

#define C1     0.72134752f   // 0.5*log2(e); exp(-z^2/2) = exp2(-C1*z^2)
#define SQRT_C 0.84932180f   // sqrt(C1)
#define WWK    1.2023651f    // MEX_C / C1, MEX_C = 2/(sqrt(3)*pi^0.25)
#define LOG2E  1.44269504f

typedef float v2f __attribute__((ext_vector_type(2)));

// softplus(scale)+0.1 -> packed wavelet params, identical math to old prep
__device__ __forceinline__ float4 wk_transform(float sc, float tr, float w_w, float b_w) {
    float sp  = fmaxf(sc, 0.0f) + log1pf(__expf(-fabsf(sc)));  // stable softplus
    float is2 = SQRT_C / (sp + 0.1f);
    float4 w;
    w.x = tr * is2;
    w.y = is2;
    w.z = w_w * WWK;
    w.w = b_w;
    return w;
}

__global__ __launch_bounds__(BLOCK, 8) void wavekan_main(
    const float* __restrict__ x,
    const float* __restrict__ scale,
    const float* __restrict__ trans,
    const float* __restrict__ ww,
    const float* __restrict__ bw,
    const float* __restrict__ gamma,
    const float* __restrict__ beta,
    float* __restrict__ out,
    int N)
{
    // s_x[d * XSTRIDE + pair] = {ln_row0, ln_row1, raw_row0, raw_row1}
    __shared__ float4 s_x[D_DIM * XSTRIDE];          // 18 KB
    __shared__ float4 s_w[CHUNK * O_DIM];            // 32 KB

    const int tid  = threadIdx.x;
    const int row0 = blockIdx.x * ROWS;

    // ---- Phase 1: one wave per row (64 lanes x 2 elems), LayerNorm -> LDS ----
    {
        const int r  = tid >> 6;        // local row 0..15 == wave id
        const int j  = tid & 63;        // lane
        const int d0 = j * 2;           // 2 elems per lane
        const int grow = row0 + r;

        float2 v2 = make_float2(0.f, 0.f);
        if (grow < N)
            v2 = *reinterpret_cast<const float2*>(x + (size_t)grow * D_DIM + d0);

        float sum = v2.x + v2.y;
        float ssq = v2.x * v2.x + v2.y * v2.y;
        #pragma unroll
        for (int m = 1; m < 64; m <<= 1) {   // full-wave butterfly
            sum += __shfl_xor(sum, m, 64);
            ssq += __shfl_xor(ssq, m, 64);
        }
        const float mean = sum * (1.0f / D_DIM);
        const float var  = ssq * (1.0f / D_DIM) - mean * mean;
        const float rstd = rsqrtf(var + 1e-5f);

        float2 g2 = *reinterpret_cast<const float2*>(gamma + d0);
        float2 b2 = *reinterpret_cast<const float2*>(beta + d0);

        const int p  = r >> 1;          // pair index 0..7
        const int h  = r & 1;           // which row of the pair
        float* c0 = reinterpret_cast<float*>(&s_x[d0 * XSTRIDE + p]);
        float* c1 = reinterpret_cast<float*>(&s_x[(d0 + 1) * XSTRIDE + p]);
        c0[h]     = (v2.x - mean) * rstd * g2.x + b2.x;   // ln
        c0[2 + h] = v2.x;                                  // raw
        c1[h]     = (v2.y - mean) * rstd * g2.y + b2.y;
        c1[2 + h] = v2.y;
    }

    // ---- Weight staging ids: thread -> (o = tid>>3, d-pair sq = tid&7) ----
    // per wave: 8 o-rows x 8 d-pairs -> reads are 8 fully-used 64B segments.
    const int so    = tid >> 3;               // 0..127
    const int sq    = tid & 7;                // 0..7 (d-pair within chunk)
    const int wbase = so * D_DIM + sq * 2;    // + c*CHUNK

    // Prologue: load + transform chunk 0 into registers
    float4 r0, r1;
    {
        float2 sc2 = *reinterpret_cast<const float2*>(scale + wbase);
        float2 tr2 = *reinterpret_cast<const float2*>(trans + wbase);
        float2 wv2 = *reinterpret_cast<const float2*>(ww    + wbase);
        float2 bv2 = *reinterpret_cast<const float2*>(bw    + wbase);
        r0 = wk_transform(sc2.x, tr2.x, wv2.x, bv2.x);
        r1 = wk_transform(sc2.y, tr2.y, wv2.y, bv2.y);
    }

    // ---- Phase 2: thread = column o x 2 rows; weights via LDS chunks ----
    const int o = tid & (O_DIM - 1);
    const int g = tid >> 7;  // pair 0..7

    v2f accw = {0.f, 0.f};
    v2f accb = {0.f, 0.f};

    for (int c = 0; c < NCHUNK; ++c) {
        __syncthreads();              // prev chunk compute done (+phase-1 at c=0)
        s_w[(sq * 2)     * O_DIM + so] = r0;   // b128 writes, 8 lanes/bank-group
        s_w[(sq * 2 + 1) * O_DIM + so] = r1;   // uniform -> ~optimal for b128
        __syncthreads();              // staging visible

        // issue next chunk's raw loads early; transform lands after compute
        float2 sc2, tr2, wv2, bv2;
        const bool more = (c + 1 < NCHUNK);
        if (more) {
            const int off = wbase + (c + 1) * CHUNK;
            sc2 = *reinterpret_cast<const float2*>(scale + off);
            tr2 = *reinterpret_cast<const float2*>(trans + off);
            wv2 = *reinterpret_cast<const float2*>(ww    + off);
            bv2 = *reinterpret_cast<const float2*>(bw    + off);
        }

        #pragma unroll
        for (int dl = 0; dl < CHUNK; ++dl) {
            float4 w  = s_w[dl * O_DIM + o];                 // per-lane b128, conflict-free
            float4 xx = s_x[(c * CHUNK + dl) * XSTRIDE + g]; // broadcast b128
            v2f xln = {xx.x, xx.y};
            v2f xrw = {xx.z, xx.w};
            v2f u   = xln * w.y - w.x;       // pk_fma
            v2f q   = u * u;
            v2f s1  = q - C1;
            v2f e   = {__builtin_amdgcn_exp2f(-q.x),
                       __builtin_amdgcn_exp2f(-q.y)};
            accw += (s1 * e) * w.z;
            accb += xrw * w.w;
        }

        if (more) {
            r0 = wk_transform(sc2.x, tr2.x, wv2.x, bv2.x);
            r1 = wk_transform(sc2.y, tr2.y, wv2.y, bv2.y);
        }
    }

    // ---- Epilogue: out = wavelet + silu(base) ----
    {
        const int rr0 = row0 + g * 2;
        if (rr0 < N) {
            float sig0 = 1.0f / (1.0f + __builtin_amdgcn_exp2f(-LOG2E * accb.x));
            out[(size_t)rr0 * O_DIM + o] = accw.x + accb.x * sig0;
        }
        if (rr0 + 1 < N) {
            float sig1 = 1.0f / (1.0f + __builtin_amdgcn_exp2f(-LOG2E * accb.y));
            out[(size_t)(rr0 + 1) * O_DIM + o] = accw.y + accb.y * sig1;
        }
    }
}

extern "C" void kernel_launch(void* const* d_in, const int* in_sizes, int n_in,
                              void* d_out, int out_size, void* d_ws, size_t ws_size,
                              hipStream_t stream) {
    const float* x     = (const float*)d_in[0];
    const float* scale = (const float*)d_in[1];
    const float* trans = (const float*)d_in[2];
    const float* ww    = (const float*)d_in[3];
    const float* bw    = (const float*)d_in[4];
    const float* gamma = (const float*)d_in[5];
    const float* beta  = (const float*)d_in[6];
    float* out = (float*)d_out;

    const int N = in_sizes[0] / D_DIM;       // 8192
    const int grid = (N + ROWS - 1) / ROWS;  // 512

    // NOTE: d_ws deliberately untouched -- testing whether the 256MB
    // workspace poison fills (2 x 40.8us) leave the timed path.
    (void)d_ws; (void)ws_size;

    wavekan_main<<<grid, BLOCK, 0, stream>>>(
        x, scale, trans, ww, bw, gamma, beta, out, N);
}